// Round 4
// baseline (476.454 us; speedup 1.0000x reference)
//
#include <hip/hip_runtime.h>

// ScaledDotProductAttention: b=16, n=2048, d=64, causal, temp=8.
// Outputs concatenated in d_out: out [b,n,d] fp32, attn [b,n,n] fp32.
//
// Round 6: overlap the attn write stream with flash compute.
//  - 512 uniform blocks (8 waves). Block handles TWO 32-row q-tiles
//    (rt=u and rt=63-u -> exactly 33 K-tiles, 512 KB attn per block).
//  - Tile A: flash only. Tile B: flash loop with tile-A's attn stream
//    INTERLEAVED (swapped-operand MFMA from L2-hot K, no barriers,
//    fire-and-forget float4 stores fill barrier slack + keep HBM busy).
//    Tile B's stream drains at the end.
//  - Co-resident blocks anti-phased (heavy-first vs light-first by
//    ((x>>3)^(x>>8))&1) so tail streams land at different times.
//  - XCD-affinity swizzle keeps K/V/Q L2-resident (3 MB/XCD).

constexpr int B = 16;
constexpr int N = 2048;
constexpr int D = 64;
constexpr float INV_TEMP = 0.125f; // 1/8

typedef __attribute__((ext_vector_type(8))) short bf16x8; // 8 bf16 in 4 VGPRs
typedef __attribute__((ext_vector_type(4))) float f32x4;

__device__ __forceinline__ short f2bf(float f) {
    __bf16 h = (__bf16)f;
    return __builtin_bit_cast(short, h);
}

__global__ __launch_bounds__(512) void sdpa_fused3(
    const float* __restrict__ q,
    const float* __restrict__ k,
    const float* __restrict__ v,
    float* __restrict__ out,
    float* __restrict__ attn)
{
    __shared__ __align__(16) short sK[2][64][72];  // K tile, double-buffered
    __shared__ __align__(16) short sV[2][64][72];  // V^T tile: sV[buf][d][kr]
    __shared__ __align__(16) short sPt[32][72];    // Q stage, then per-tile P
    __shared__ float rsum[128];                    // [8 waves][16 rows]
    __shared__ float sinv2[2][32];                 // per-phase 1/rowsum

    const int x   = blockIdx.x;
    const int xcd = x & 7;
    const int idx = x >> 3;               // 0..63
    const int b   = xcd * 2 + (idx & 1);  // batch (2 batches per XCD)
    const int u   = idx >> 1;             // 0..31
    const int hf  = ((x >> 3) ^ (x >> 8)) & 1;   // anti-phase ordering bit

    const int rtA = hf ? (63 - u) : u;    // first tile
    const int rtB = hf ? u : (63 - u);    // second tile

    const int t    = threadIdx.x;
    const int w    = t >> 6;              // wave 0..7
    const int lane = t & 63;
    const int l15  = lane & 15;
    const int quad = lane >> 4;           // 0..3
    const int q8   = quad * 8;
    const int rg   = w & 1;               // row-group (16 rows) of the 32-row tile
    const int cg   = w >> 1;              // col-group (16 cols) of the 64-col K tile

    const float* qb = q + (size_t)b * N * D;
    const float* kb = k + (size_t)b * N * D;
    const float* vb = v + (size_t)b * N * D;
    float* attn_b = attn + (size_t)b * N * N;

    const int krow = t >> 3;              // staging row 0..63
    const int kc8  = (t & 7) * 8;         // staging d-chunk start (8 floats)

    // one attn col-tile (64 cols) for a previously-flashed q-tile; per-wave,
    // no LDS, no barriers. a0/a1 = that tile's Q frags (swapped-op B operand).
    auto stream_tile = [&](int ct, bf16x8 a0, bf16x8 a1, float einv,
                           int qrow, int rmax, float* arow) {
        const int c0  = ct * 64 + cg * 16;
        const int kg0 = c0 + quad * 4;
        float4 pv4;
        if (c0 <= rmax) {                 // wave-uniform live check
            const float* kr = kb + (size_t)(c0 + l15) * D;
            const float4* kp = (const float4*)(kr + q8);
            float4 k0 = kp[0], k1 = kp[1];
            const float4* kp2 = (const float4*)(kr + 32 + q8);
            float4 k2 = kp2[0], k3 = kp2[1];
            float kv[16] = {k0.x,k0.y,k0.z,k0.w, k1.x,k1.y,k1.z,k1.w,
                            k2.x,k2.y,k2.z,k2.w, k3.x,k3.y,k3.z,k3.w};
            bf16x8 kb0, kb1;
#pragma unroll
            for (int i = 0; i < 8; ++i) { kb0[i] = f2bf(kv[i]); kb1[i] = f2bf(kv[8 + i]); }
            // swapped operands: C = K . Q^T -> lane holds S[kg0..kg0+3][qrow]
            f32x4 c = {0.f, 0.f, 0.f, 0.f};
            c = __builtin_amdgcn_mfma_f32_16x16x32_bf16(kb0, a0, c, 0, 0, 0);
            c = __builtin_amdgcn_mfma_f32_16x16x32_bf16(kb1, a1, c, 0, 0, 0);
            pv4.x = (kg0 + 0 <= qrow) ? __expf(c[0] * INV_TEMP) * einv : 0.f;
            pv4.y = (kg0 + 1 <= qrow) ? __expf(c[1] * INV_TEMP) * einv : 0.f;
            pv4.z = (kg0 + 2 <= qrow) ? __expf(c[2] * INV_TEMP) * einv : 0.f;
            pv4.w = (kg0 + 3 <= qrow) ? __expf(c[3] * INV_TEMP) * einv : 0.f;
        } else {
            pv4 = {0.f, 0.f, 0.f, 0.f};
        }
        *(float4*)(arow + kg0) = pv4;
    };

    // flash phase for one 32-row q-tile. Optionally interleaves the attn
    // stream of a previously-flashed tile (sa0/sa1/seinv/sqrow/srmax/sarow).
    auto flash = [&](int rt, int slot, bf16x8& qa0o, bf16x8& qa1o,
                     bool inter, bf16x8 sa0, bf16x8 sa1, float seinv,
                     int sqrow, int srmax, float* sarow) {
        const int qs_ = rt * 32;
        const int nt  = (rt >> 1) + 1;

        // prefetch K/V tile 0 into registers
        float4 kf0, kf1;
        float  vr[8];
        {
            const float4* s = (const float4*)(kb + (size_t)krow * D + kc8);
            kf0 = s[0]; kf1 = s[1];
            const float* sv = vb + (size_t)(w * 8) * D + lane;
#pragma unroll
            for (int i = 0; i < 8; ++i) vr[i] = sv[(size_t)i * D];
        }

        __syncthreads();   // previous phase fully done with sPt
        if (t < 256) {     // stage Q tile -> sPt (bf16)
            const float4* s = (const float4*)(qb + (size_t)(qs_ + krow) * D + kc8);
            float4 a = s[0], c4 = s[1];
            float qv[8] = {a.x,a.y,a.z,a.w, c4.x,c4.y,c4.z,c4.w};
            bf16x8 pq;
#pragma unroll
            for (int i = 0; i < 8; ++i) pq[i] = f2bf(qv[i]);
            *(bf16x8*)&sPt[krow][kc8] = pq;
        }
        __syncthreads();
        const bf16x8 qa0 = *(const bf16x8*)&sPt[rg * 16 + l15][q8];
        const bf16x8 qa1 = *(const bf16x8*)&sPt[rg * 16 + l15][32 + q8];
        qa0o = qa0; qa1o = qa1;

        float rs[4] = {0.f, 0.f, 0.f, 0.f};
        f32x4 o = {0.f, 0.f, 0.f, 0.f};
        int sc = 0;                          // stream cursor (col-tiles 0..31)

        for (int kt = 0; kt < nt; ++kt) {
            const int cur = kt & 1;
            {   // staged regs -> LDS (b128 writes, bank-uniform)
                float kv[8] = {kf0.x,kf0.y,kf0.z,kf0.w, kf1.x,kf1.y,kf1.z,kf1.w};
                bf16x8 pk, pv;
#pragma unroll
                for (int i = 0; i < 8; ++i) pk[i] = f2bf(kv[i]);
#pragma unroll
                for (int i = 0; i < 8; ++i) pv[i] = f2bf(vr[i]);
                *(bf16x8*)&sK[cur][krow][kc8]  = pk;   // K[kr][d]
                *(bf16x8*)&sV[cur][lane][w*8]  = pv;   // V^T: sV[d][kr]
            }
            __syncthreads();  // staging visible; prev PV / Q-frag reads done
            if (kt + 1 < nt) {  // T14: next tile's global loads in flight
                const float4* s = (const float4*)(kb + (size_t)((kt+1)*64 + krow) * D + kc8);
                kf0 = s[0]; kf1 = s[1];
                const float* sv = vb + (size_t)((kt+1)*64 + w*8) * D + lane;
#pragma unroll
                for (int i = 0; i < 8; ++i) vr[i] = sv[(size_t)i * D];
            }
            // S subtile (rg, cg): 16x16 over K=64
            bf16x8 b0 = *(const bf16x8*)&sK[cur][cg * 16 + l15][q8];
            bf16x8 b1 = *(const bf16x8*)&sK[cur][cg * 16 + l15][32 + q8];
            f32x4 c = {0.f, 0.f, 0.f, 0.f};
            c = __builtin_amdgcn_mfma_f32_16x16x32_bf16(qa0, b0, c, 0, 0, 0);
            c = __builtin_amdgcn_mfma_f32_16x16x32_bf16(qa1, b1, c, 0, 0, 0);
            const int colg = kt * 64 + cg * 16 + l15;
#pragma unroll
            for (int r = 0; r < 4; ++r) {
                const int rowg = qs_ + rg * 16 + quad * 4 + r;
                float pr = (colg <= rowg) ? __expf(c[r] * INV_TEMP) : 0.f;
                rs[r] += pr;
                sPt[rg * 16 + quad * 4 + r][cg * 16 + l15] = f2bf(pr);
            }
            // interleaved attn stream of the previous tile (per-wave, no LDS):
            // fills barrier slack, keeps HBM writes flowing during compute.
            if (inter) {
                const int se = (32 * (kt + 1)) / nt;   // reaches 32 at kt=nt-1
                for (; sc < se; ++sc)
                    stream_tile(sc, sa0, sa1, seinv, sqrow, srmax, sarow);
            }
            __syncthreads();  // cross-wave P columns ready
            // PV: O(rg,cg) += P(rg, tile) . V(tile, cg)
#pragma unroll
            for (int kc = 0; kc < 2; ++kc) {
                bf16x8 a  = *(const bf16x8*)&sPt[rg * 16 + l15][kc * 32 + q8];
                bf16x8 vf = *(const bf16x8*)&sV[cur][cg * 16 + l15][kc * 32 + q8];
                o = __builtin_amdgcn_mfma_f32_16x16x32_bf16(a, vf, o, 0, 0, 0);
            }
        }

        // row-sum reduction
#pragma unroll
        for (int r = 0; r < 4; ++r) {
            float s = rs[r];
            s += __shfl_xor(s, 1);
            s += __shfl_xor(s, 2);
            s += __shfl_xor(s, 4);
            s += __shfl_xor(s, 8);
            rs[r] = s;
        }
        if (l15 == 0) {
#pragma unroll
            for (int r = 0; r < 4; ++r) rsum[w * 16 + quad * 4 + r] = rs[r];
        }
        __syncthreads();
        if (t < 32) {
            const int rg2 = t >> 4, rl = t & 15;
            float tot = rsum[(rg2 + 0) * 16 + rl] + rsum[(rg2 + 2) * 16 + rl]
                      + rsum[(rg2 + 4) * 16 + rl] + rsum[(rg2 + 6) * 16 + rl];
            sinv2[slot][t] = 1.f / tot;
        }
        __syncthreads();

        // write O (normalized)
#pragma unroll
        for (int r = 0; r < 4; ++r) {
            const int rowl = rg * 16 + quad * 4 + r;
            out[(size_t)(b * N + qs_ + rowl) * D + cg * 16 + l15]
                = o[r] * sinv2[slot][rowl];
        }
    };

    // ---- phase A: flash tile A (no stream available yet) ----
    bf16x8 qaA0, qaA1, qaB0, qaB1;
    bf16x8 dummy = {};
    flash(rtA, 0, qaA0, qaA1, false, dummy, dummy, 0.f, 0, 0, nullptr);

    const float einvA = sinv2[0][rg * 16 + l15];
    const int   qrowA = rtA * 32 + rg * 16 + l15;
    const int   rmaxA = rtA * 32 + rg * 16 + 15;
    float* arowA = attn_b + (size_t)qrowA * N;

    // ---- phase B: flash tile B with tile-A's attn stream interleaved ----
    flash(rtB, 1, qaB0, qaB1, true, qaA0, qaA1, einvA, qrowA, rmaxA, arowA);

    // ---- drain: tile-B's attn stream (full N cols: live + zeros) ----
    const float einvB = sinv2[1][rg * 16 + l15];
    const int   qrowB = rtB * 32 + rg * 16 + l15;
    const int   rmaxB = rtB * 32 + rg * 16 + 15;
    float* arowB = attn_b + (size_t)qrowB * N;
    for (int ct = 0; ct < 32; ++ct)
        stream_tile(ct, qaB0, qaB1, einvB, qrowB, rmaxB, arowB);
}

extern "C" void kernel_launch(void* const* d_in, const int* in_sizes, int n_in,
                              void* d_out, int out_size, void* d_ws, size_t ws_size,
                              hipStream_t stream) {
    const float* q = (const float*)d_in[0];
    const float* k = (const float*)d_in[1];
    const float* v = (const float*)d_in[2];
    // d_in[3] (mask) is static causal — not read.

    float* out  = (float*)d_out;
    float* attn = out + (size_t)B * N * D;

    sdpa_fused3<<<dim3(B * 32), dim3(512), 0, stream>>>(q, k, v, out, attn);
}